// Round 1
// baseline (255.409 us; speedup 1.0000x reference)
//
#include <hip/hip_runtime.h>
#include <math.h>

// Problem shape (fixed by setup_inputs): x (16, 512, 512, 8) float32, NHWC.
constexpr int Hdim = 512;
constexpr int Wdim = 512;
// float4-granule layout: flat idx bits = n(4) | h(9) | w(9) | c4(1)

__global__ __launch_bounds__(256) void nms_kernel(
    const float4* __restrict__ x,
    const unsigned char* __restrict__ mask_bytes,
    float4* __restrict__ out,
    int total4)
{
    // ---- Decode 3x3 boolean mask robustly (harness may pass bool as int32
    // or as 1-byte bool). If it's 1-byte layout, reading as int32 yields
    // values like 0x01010101 which are not in {0,1} -> detect and fall back.
    const int* mask_ints = (const int*)mask_bytes;
    bool int_layout = true;
    #pragma unroll
    for (int i = 0; i < 9; ++i) {
        int v = mask_ints[i];
        int_layout = int_layout && (v == 0 || v == 1);
    }
    unsigned mbits = 0;
    #pragma unroll
    for (int i = 0; i < 9; ++i) {
        bool b = int_layout ? (mask_ints[i] != 0) : (mask_bytes[i] != 0);
        mbits |= (unsigned)b << i;
    }

    int idx = blockIdx.x * blockDim.x + threadIdx.x;
    if (idx >= total4) return;

    int w = (idx >> 1) & (Wdim - 1);
    int h = (idx >> 10) & (Hdim - 1);

    float4 c = x[idx];
    float mx = -INFINITY, my = -INFINITY, mz = -INFINITY, mw = -INFINITY;

    #pragma unroll
    for (int di = 0; di < 3; ++di) {
        int hh = h + di - 1;
        bool hok = (hh >= 0) && (hh < Hdim);
        #pragma unroll
        for (int dj = 0; dj < 3; ++dj) {
            if (!((mbits >> (di * 3 + dj)) & 1u)) continue;  // wave-uniform
            int ww = w + dj - 1;
            bool ok = hok && (ww >= 0) && (ww < Wdim);
            if (ok) {
                // neighbor float4 index: shift h by (di-1) -> +/- Wdim*2,
                // shift w by (dj-1) -> +/- 2 (C=8 floats = 2 float4s / pixel)
                float4 v = x[idx + ((di - 1) * Wdim + (dj - 1)) * 2];
                mx = fmaxf(mx, v.x);
                my = fmaxf(my, v.y);
                mz = fmaxf(mz, v.z);
                mw = fmaxf(mw, v.w);
            }
        }
    }

    float4 o;
    o.x = (c.x > mx) ? c.x : 0.0f;
    o.y = (c.y > my) ? c.y : 0.0f;
    o.z = (c.z > mz) ? c.z : 0.0f;
    o.w = (c.w > mw) ? c.w : 0.0f;
    out[idx] = o;
}

extern "C" void kernel_launch(void* const* d_in, const int* in_sizes, int n_in,
                              void* d_out, int out_size, void* d_ws, size_t ws_size,
                              hipStream_t stream) {
    const float4* x = (const float4*)d_in[0];
    const unsigned char* mask = (const unsigned char*)d_in[1];
    float4* out = (float4*)d_out;

    int total4 = out_size / 4;              // 8,388,608 float4 granules
    int block = 256;
    int grid = (total4 + block - 1) / block; // 32768 blocks
    nms_kernel<<<grid, block, 0, stream>>>(x, mask, out, total4);
}

// Round 2
// 238.235 us; speedup vs baseline: 1.0721x; 1.0721x over previous
//
#include <hip/hip_runtime.h>
#include <math.h>

// x: (16, 512, 512, 8) float32 NHWC. float4 granule index:
//   f4idx = ((n*512 + h)*512 + w)*2 + c4,  c4 in {0,1}
// Thread owns a column (n, w, c4), produces HPT consecutive h outputs with a
// rolling 3-row window in registers: 3 loads per output instead of 9.

constexpr int Hdim = 512;
constexpr int Wdim = 512;
constexpr int HPT  = 8;
constexpr int ROW  = Wdim * 2;   // f4 stride between rows

__device__ __forceinline__ float4 f4max(float4 a, float4 b) {
    return make_float4(fmaxf(a.x,b.x), fmaxf(a.y,b.y), fmaxf(a.z,b.z), fmaxf(a.w,b.w));
}

__global__ __launch_bounds__(256) void nms_kernel(
    const float4* __restrict__ x,
    const unsigned char* __restrict__ mask_bytes,
    float4* __restrict__ out)
{
    // ---- Decode 3x3 boolean mask robustly (int32 vs 1-byte bool layout).
    const int* mi = (const int*)mask_bytes;
    bool intlay = true;
    #pragma unroll
    for (int i = 0; i < 9; ++i) { int v = mi[i]; intlay = intlay && (v == 0 || v == 1); }
    bool m[9];
    #pragma unroll
    for (int i = 0; i < 9; ++i) m[i] = intlay ? (mi[i] != 0) : (mask_bytes[i] != 0);

    int gid = blockIdx.x * blockDim.x + threadIdx.x;
    int c4 = gid & 1;
    int w  = (gid >> 1) & (Wdim - 1);
    int hg = (gid >> 10) & 63;          // 512/HPT = 64 h-groups
    int n  = gid >> 16;
    int h0 = hg * HPT;

    const float4 NEG = make_float4(-INFINITY, -INFINITY, -INFINITY, -INFINITY);
    bool aok = (w > 0), cok = (w < Wdim - 1);
    int ao = aok ? -2 : 0;              // clamped address offsets (value fixed below)
    int co = cok ?  2 : 0;

    long base = ((long)((n * Hdim + h0) * Wdim + w)) * 2 + c4;

    // load one row's 3 columns (a = w-1, b = w, c = w+1)
    auto loadrow = [&](long rb, float4& a, float4& b, float4& c) {
        float4 at = x[rb + ao];
        b         = x[rb];
        float4 ct = x[rb + co];
        a = aok ? at : NEG;             // only 2 lanes per edge wave diverge
        c = cok ? ct : NEG;
    };

    // masked vertical max with wave-uniform mask bits
    auto vmax = [&](float4 r0, float4 r1, float4 r2, bool b0, bool b1, bool b2) {
        float4 v = NEG;
        if (b0) v = f4max(v, r0);
        if (b1) v = f4max(v, r1);
        if (b2) v = f4max(v, r2);
        return v;
    };

    float4 a0, b0, c0, a1, b1, c1;
    if (h0 > 0) loadrow(base - ROW, a0, b0, c0);   // uniform branch
    else        { a0 = NEG; b0 = NEG; c0 = NEG; }
    loadrow(base, a1, b1, c1);

    #pragma unroll
    for (int s = 0; s < HPT; ++s) {
        int h = h0 + s;
        float4 a2, b2, c2;
        if (h + 1 < Hdim) loadrow(base + (long)(s + 1) * ROW, a2, b2, c2);  // uniform
        else              { a2 = NEG; b2 = NEG; c2 = NEG; }

        // mask[di][dj]: column dj uses bits m[dj], m[3+dj], m[6+dj] on rows h-1,h,h+1
        float4 va = vmax(a0, a1, a2, m[0], m[3], m[6]);
        float4 vb = vmax(b0, b1, b2, m[1], m[4], m[7]);
        float4 vc = vmax(c0, c1, c2, m[2], m[5], m[8]);
        float4 mm = f4max(f4max(va, vb), vc);

        float4 ctr = b1;
        float4 o;
        o.x = (ctr.x > mm.x) ? ctr.x : 0.0f;
        o.y = (ctr.y > mm.y) ? ctr.y : 0.0f;
        o.z = (ctr.z > mm.z) ? ctr.z : 0.0f;
        o.w = (ctr.w > mm.w) ? ctr.w : 0.0f;
        out[base + (long)s * ROW] = o;

        a0 = a1; a1 = a2;
        b0 = b1; b1 = b2;
        c0 = c1; c1 = c2;
    }
}

extern "C" void kernel_launch(void* const* d_in, const int* in_sizes, int n_in,
                              void* d_out, int out_size, void* d_ws, size_t ws_size,
                              hipStream_t stream) {
    const float4* x = (const float4*)d_in[0];
    const unsigned char* mask = (const unsigned char*)d_in[1];
    float4* out = (float4*)d_out;

    // total threads = 16 * (512/HPT) * 512 * 2 = 1,048,576
    int total = 16 * (Hdim / HPT) * Wdim * 2;
    int block = 256;
    int grid = total / block;   // 4096
    nms_kernel<<<grid, block, 0, stream>>>(x, mask, out);
}

// Round 3
// 232.093 us; speedup vs baseline: 1.1005x; 1.0265x over previous
//
#include <hip/hip_runtime.h>
#include <math.h>

// x: (16, 512, 512, 8) float32 NHWC. float4 granule index:
//   f4idx = ((n*512 + h)*512 + w)*2 + c4,  c4 in {0,1}
// Thread owns a column (n, w, c4) and produces HPT=8 consecutive h outputs.
// ALL 30 window loads (10 rows x {w-1, w, w+1}) are issued up front,
// branchless (clamped addresses), so the compiler can keep ~30 loads in
// flight per wave (MLP) instead of serializing on vmcnt(0) per step.

constexpr int Hdim = 512;
constexpr int Wdim = 512;
constexpr int HPT  = 8;
constexpr int ROWS = HPT + 2;
constexpr int ROW  = Wdim * 2;   // f4 stride between rows

__device__ __forceinline__ float4 f4max(float4 a, float4 b) {
    return make_float4(fmaxf(a.x,b.x), fmaxf(a.y,b.y), fmaxf(a.z,b.z), fmaxf(a.w,b.w));
}

__global__ __launch_bounds__(256) void nms_kernel(
    const float4* __restrict__ x,
    const unsigned char* __restrict__ mask_bytes,
    float4* __restrict__ out)
{
    // ---- Decode 3x3 boolean mask robustly (int32 vs 1-byte bool layout).
    const int* mi = (const int*)mask_bytes;
    bool intlay = true;
    #pragma unroll
    for (int i = 0; i < 9; ++i) { int v = mi[i]; intlay = intlay && (v == 0 || v == 1); }
    bool m[9];
    #pragma unroll
    for (int i = 0; i < 9; ++i) m[i] = intlay ? (mi[i] != 0) : (mask_bytes[i] != 0);

    int gid = blockIdx.x * blockDim.x + threadIdx.x;
    int c4 = gid & 1;
    int w  = (gid >> 1) & (Wdim - 1);
    int hg = (gid >> 10) & 63;          // 512/HPT = 64 h-groups; uniform per block
    int n  = gid >> 16;
    int h0 = hg * HPT;

    const float4 NEG = make_float4(-INFINITY, -INFINITY, -INFINITY, -INFINITY);
    bool aok = (w > 0), cok = (w < Wdim - 1);
    int ao = aok ? -2 : 0;              // clamped w-offsets (NEG-fixed later)
    int co = cok ?  2 : 0;

    int base = ((n * Hdim + h0) * Wdim + w) * 2 + c4;

    // ---- Issue ALL loads up front, branchless (rows clamped; fixed later).
    float4 A[ROWS], B[ROWS], C[ROWS];
    #pragma unroll
    for (int r = 0; r < ROWS; ++r) {
        int hr = h0 - 1 + r;
        int hc = hr < 0 ? 0 : (hr > Hdim - 1 ? Hdim - 1 : hr);
        int rb = base + (hc - h0) * ROW;
        A[r] = x[rb + ao];
        B[r] = x[rb];
        C[r] = x[rb + co];
    }

    bool topclamp = (h0 == 0);            // block-uniform
    bool botclamp = (h0 + HPT == Hdim);   // block-uniform

    #pragma unroll
    for (int s = 0; s < HPT; ++s) {
        bool r0ok = !(s == 0 && topclamp);       // block-uniform
        bool r2ok = !(s == HPT - 1 && botclamp); // block-uniform

        float4 va = NEG, vb = NEG, vc = NEG;
        if (m[0] && r0ok) va = f4max(va, A[s]);
        if (m[3])         va = f4max(va, A[s + 1]);
        if (m[6] && r2ok) va = f4max(va, A[s + 2]);
        if (m[1] && r0ok) vb = f4max(vb, B[s]);
        if (m[4])         vb = f4max(vb, B[s + 1]);
        if (m[7] && r2ok) vb = f4max(vb, B[s + 2]);
        if (m[2] && r0ok) vc = f4max(vc, C[s]);
        if (m[5])         vc = f4max(vc, C[s + 1]);
        if (m[8] && r2ok) vc = f4max(vc, C[s + 2]);

        // w-edge fixup (per-lane, 2 lanes per 512)
        va.x = aok ? va.x : -INFINITY; va.y = aok ? va.y : -INFINITY;
        va.z = aok ? va.z : -INFINITY; va.w = aok ? va.w : -INFINITY;
        vc.x = cok ? vc.x : -INFINITY; vc.y = cok ? vc.y : -INFINITY;
        vc.z = cok ? vc.z : -INFINITY; vc.w = cok ? vc.w : -INFINITY;

        float4 mm = f4max(f4max(va, vb), vc);
        float4 ctr = B[s + 1];
        float4 o;
        o.x = (ctr.x > mm.x) ? ctr.x : 0.0f;
        o.y = (ctr.y > mm.y) ? ctr.y : 0.0f;
        o.z = (ctr.z > mm.z) ? ctr.z : 0.0f;
        o.w = (ctr.w > mm.w) ? ctr.w : 0.0f;
        out[base + s * ROW] = o;
    }
}

extern "C" void kernel_launch(void* const* d_in, const int* in_sizes, int n_in,
                              void* d_out, int out_size, void* d_ws, size_t ws_size,
                              hipStream_t stream) {
    const float4* x = (const float4*)d_in[0];
    const unsigned char* mask = (const unsigned char*)d_in[1];
    float4* out = (float4*)d_out;

    // total threads = 16 * (512/HPT) * 512 * 2 = 1,048,576
    int total = 16 * (Hdim / HPT) * Wdim * 2;
    int block = 256;
    int grid = total / block;   // 4096
    nms_kernel<<<grid, block, 0, stream>>>(x, mask, out);
}